// Round 7
// baseline (154.100 us; speedup 1.0000x reference)
//
#include <hip/hip_runtime.h>

// RoIAlign (max-pool variant) for MI355X — fp32, R7.
//  K1: LDS-tiled transpose (B,C,HW) -> (B,HW,C)  (unchanged).
//  K2: grid (N, 2): block = (roi, bin-half). half0 = bins 0..24, half1 =
//      bins 25..48, all 256 channels; lane = 4 channels (float4). LDS stage
//      drops to ~26 KB -> 5 blocks/CU (20 waves/CU, was 12) and 2048 blocks
//      smooth the dispatch tail. Phase 2 processes bins in PAIRS: both 9-
//      float4 patch loads issued before either compute, so the second bin's
//      loads are in flight during the first bin's math (partial-vmcnt
//      pipelining). 3x3-patch + (ax,ay) corner-select as in R6.
// Numerics identical to R2-R6 (same per-component op order) — absmax 0.0156.

namespace {

constexpr int B_ = 4, C_ = 256, H_ = 50, W_ = 50;
constexpr int HW = H_ * W_;                     // 2500
constexpr int HO = 7, WO = 7, NBIN = HO * WO;   // 49
constexpr int OUT_PER_ROI = C_ * NBIN;          // 12544
constexpr int MAXB = 25;                        // bins per half (25 or 24)
constexpr int LD = 260;                         // stage leading dim (mult of 4)
constexpr float RATIO = 1.0f / 32.0f;

// ---------------- K1: tiled transpose (B,C,HW) -> (B,HW,C) ----------------
__global__ __launch_bounds__(256) void transpose_tiled(
    const float* __restrict__ f, float* __restrict__ ft)
{
    __shared__ float tile[64][65];
    const int bt   = blockIdx.x;
    const int hw_t = bt % 40;
    const int c_t  = (bt / 40) % 4;
    const int b    = bt / 160;
    const int hw0 = hw_t * 64, c0 = c_t * 64;
    const int lx = threadIdx.x & 63;
    const int ly = threadIdx.x >> 6;

#pragma unroll
    for (int k = 0; k < 16; ++k) {
        const int c  = c0 + k * 4 + ly;
        const int hw = hw0 + lx;
        if (hw < HW)
            tile[k * 4 + ly][lx] = f[((size_t)b * C_ + c) * HW + hw];
    }
    __syncthreads();
#pragma unroll
    for (int k = 0; k < 16; ++k) {
        const int hw = hw0 + k * 4 + ly;
        if (hw < HW)
            ft[((size_t)b * HW + hw) * C_ + c0 + lx] = tile[lx][k * 4 + ly];
    }
}

// Corner selection with compile-time patch indices (P = row-major 3x3).
template<int AX, int AY>
__device__ __forceinline__ float4 bin_max(const float4 P[9],
                                          const float4 wa, const float4 wb)
{
    float4 s[2][2];
#pragma unroll
    for (int sy = 0; sy < 2; ++sy) {
#pragma unroll
        for (int sx = 0; sx < 2; ++sx) {
            const int xk = AX * sx, yj = AY * sy;
            const float wxh = sx ? wa.y : wa.x;
            const float wxl = sx ? wa.w : wa.z;
            const float wyb = sy ? wb.y : wb.x;
            const float wyt = sy ? wb.w : wb.z;
            const float4 tl = P[yj * 3 + xk],       tr = P[yj * 3 + xk + 1];
            const float4 bl = P[(yj + 1) * 3 + xk], br = P[(yj + 1) * 3 + xk + 1];
            float4 o;
            o.x = wyb * (wxh * br.x + wxl * bl.x) + wyt * (wxh * tr.x + wxl * tl.x);
            o.y = wyb * (wxh * br.y + wxl * bl.y) + wyt * (wxh * tr.y + wxl * tl.y);
            o.z = wyb * (wxh * br.z + wxl * bl.z) + wyt * (wxh * tr.z + wxl * tl.z);
            o.w = wyb * (wxh * br.w + wxl * bl.w) + wyt * (wxh * tr.w + wxl * tl.w);
            s[sy][sx] = o;
        }
    }
    float4 m;
    m.x = fmaxf(fmaxf(s[0][0].x, s[0][1].x), fmaxf(s[1][0].x, s[1][1].x));
    m.y = fmaxf(fmaxf(s[0][0].y, s[0][1].y), fmaxf(s[1][0].y, s[1][1].y));
    m.z = fmaxf(fmaxf(s[0][0].z, s[0][1].z), fmaxf(s[1][0].z, s[1][1].z));
    m.w = fmaxf(fmaxf(s[0][0].w, s[0][1].w), fmaxf(s[1][0].w, s[1][1].w));
    return m;
}

__device__ __forceinline__ float4 bin_max_sel(unsigned fl, const float4 P[9],
                                              const float4 wa, const float4 wb)
{
    switch (fl) {                                // wave-uniform branch
        case 0u:  return bin_max<0, 0>(P, wa, wb);
        case 1u:  return bin_max<1, 0>(P, wa, wb);
        case 2u:  return bin_max<0, 1>(P, wa, wb);
        default:  return bin_max<1, 1>(P, wa, wb);
    }
}

// ---------------- K2: main ----------------
__global__ __launch_bounds__(256, 4) void roialign_main(
    const float* __restrict__ ft,       // (B,HW,C)
    const float* __restrict__ rois,
    float* __restrict__ out)
{
    __shared__ float stage[MAXB * LD];                   // 26000 B
    __shared__ __align__(16) float    wts[MAXB][8];      // wxh0,wxh1,wxl0,wxl1,wyb0,wyb1,wyt0,wyt1 (x valid)
    __shared__ __align__(16) unsigned offp[MAXB][12];    // [0..8]=3x3 hw offsets, [9]=ax|(ay<<1)

    const int n    = blockIdx.x;
    const int half = blockIdx.y;
    const int base = half * MAXB;                        // 0 or 25
    const int count = half ? (NBIN - MAXB) : MAXB;       // 25 or 24
    const int tid  = threadIdx.x;
    const int wave = tid >> 6;
    const int lane = tid & 63;
    const float fW = (float)W_, fH = (float)H_;

    // ---- Phase 1: geometry for this half's bins ----
    if (tid < count) {
        const int gbin = base + tid;
        const int ii = gbin / WO, jj = gbin % WO;
        const float* r = rois + n * 5;
        const float bx1 = fminf(fmaxf(r[1] * RATIO, 0.0f), fW);
        const float by1 = fminf(fmaxf(r[2] * RATIO, 0.0f), fH);
        const float bx2 = fminf(fmaxf(r[3] * RATIO, 0.0f), fW);
        const float by2 = fminf(fmaxf(r[4] * RATIO, 0.0f), fH);
        const bool roi_valid = (bx2 - bx1 > 0.0f) && (by2 - by1 > 0.0f);
        const float bin_w = (bx2 - bx1) * (1.0f / (float)WO);
        const float bin_h = (by2 - by1) * (1.0f / (float)HO);

        const float x1u = bx1 + (float)jj * bin_w;
        const float x1b = fminf(fmaxf(x1u, 0.0f), fW);
        const float x2b = fminf(fmaxf(x1u + bin_w, 0.0f), fW);
        const float y1u = by1 + (float)ii * bin_h;
        const float y1b = fminf(fmaxf(y1u, 0.0f), fH);
        const float y2b = fminf(fmaxf(y1u + bin_h, 0.0f), fH);
        const float vf = (roi_valid && (y2b > y1b) && (x2b > x1b)) ? 1.0f : 0.0f;

        int xl[2], yl[2];
#pragma unroll
        for (int s = 0; s < 2; ++s) {
            const float px = x1b + ((float)s + 0.5f) * (bin_w * 0.5f);
            int l = (int)floorf(px);
            l = min(max(l, 0), W_ - 1);
            const int h = min(l + 1, W_ - 1);
            xl[s] = l;
            wts[tid][0 + s] = vf * (px - (float)l);      // wxh[s]
            wts[tid][2 + s] = vf * ((float)h - px);      // wxl[s]

            const float py = y1b + ((float)s + 0.5f) * (bin_h * 0.5f);
            int t = (int)floorf(py);
            t = min(max(t, 0), H_ - 1);
            const int u = min(t + 1, H_ - 1);
            yl[s] = t;
            wts[tid][4 + s] = py - (float)t;             // wyb[s]
            wts[tid][6 + s] = (float)u - py;             // wyt[s]
        }
        const int X0 = xl[0], Y0 = yl[0];
        const int ax = min(xl[1] - X0, 1);
        const int ay = min(yl[1] - Y0, 1);
        const int px_[3] = {X0, min(X0 + 1, W_ - 1), min(X0 + 2, W_ - 1)};
        const int py_[3] = {Y0, min(Y0 + 1, H_ - 1), min(Y0 + 2, H_ - 1)};
#pragma unroll
        for (int j = 0; j < 3; ++j)
#pragma unroll
            for (int k = 0; k < 3; ++k)
                offp[tid][j * 3 + k] = (unsigned)(py_[j] * W_ + px_[k]);
        offp[tid][9]  = (unsigned)(ax | (ay << 1));
        offp[tid][10] = 0u;
        offp[tid][11] = 0u;
    }
    __syncthreads();

    // ---- Phase 2: lane = 4 channels; waves split this half's bins, paired ----
    int b = (int)rois[n * 5];
    b = min(max(b, 0), B_ - 1);
    const float4* pb = (const float4*)(ft + (size_t)b * HW * C_) + lane;

    auto issue_patch = [&](int i, float4 P[9]) {
        const uint4 o0 = *(const uint4*)&offp[i][0];     // p00 p01 p02 p10
        const uint4 o1 = *(const uint4*)&offp[i][4];     // p11 p12 p20 p21
        const unsigned p22 = offp[i][8];
        P[0] = pb[(int)o0.x << 6];
        P[1] = pb[(int)o0.y << 6];
        P[2] = pb[(int)o0.z << 6];
        P[3] = pb[(int)o0.w << 6];
        P[4] = pb[(int)o1.x << 6];
        P[5] = pb[(int)o1.y << 6];
        P[6] = pb[(int)o1.z << 6];
        P[7] = pb[(int)o1.w << 6];
        P[8] = pb[(int)p22 << 6];
    };

    for (int i = wave; i < count; i += 8) {
        const int j = i + 4;
        float4 PA[9], PB[9];
        issue_patch(i, PA);                              // loads for bin i
        if (j < count) issue_patch(j, PB);               // loads for bin j in flight
        {
            const float4 wa = *(const float4*)wts[i];
            const float4 wb = *(const float4*)(wts[i] + 4);
            const float4 m = bin_max_sel(offp[i][9], PA, wa, wb);
            *(float4*)&stage[i * LD + 4 * lane] = m;
        }
        if (j < count) {
            const float4 wa = *(const float4*)wts[j];
            const float4 wb = *(const float4*)(wts[j] + 4);
            const float4 m = bin_max_sel(offp[j][9], PB, wa, wb);
            *(float4*)&stage[j * LD + 4 * lane] = m;
        }
    }
    __syncthreads();

    // ---- Phase 3: coalesced-ish write of this half's bins ----
    float* outn = out + (size_t)n * OUT_PER_ROI + base;
    if (half == 0) {
        for (int k = tid; k < C_ * 25; k += 256) {
            const int ch = k / 25, bi = k - ch * 25;     // const divisor -> magic mul
            outn[ch * NBIN + bi] = stage[bi * LD + ch];
        }
    } else {
        for (int k = tid; k < C_ * 24; k += 256) {
            const int ch = k / 24, bi = k - ch * 24;
            outn[ch * NBIN + bi] = stage[bi * LD + ch];
        }
    }
}

} // namespace

extern "C" void kernel_launch(void* const* d_in, const int* in_sizes, int n_in,
                              void* d_out, int out_size, void* d_ws, size_t ws_size,
                              hipStream_t stream)
{
    const float* feats = (const float*)d_in[0];
    const float* rois  = (const float*)d_in[1];
    float* out = (float*)d_out;
    const int N = in_sizes[1] / 5;                    // 1024
    float* ft = (float*)d_ws;                         // 10.24 MB

    hipLaunchKernelGGL(transpose_tiled, dim3(B_ * 4 * 40), dim3(256), 0, stream,
                       feats, ft);
    hipLaunchKernelGGL(roialign_main, dim3(N, 2), dim3(256), 0, stream,
                       ft, rois, out);
}

// Round 8
// 104.951 us; speedup vs baseline: 1.4683x; 1.4683x over previous
//
#include <hip/hip_runtime.h>

// RoIAlign (max-pool variant) for MI355X — fp32, R8.
//  K1: LDS-tiled transpose (B,C,HW) -> (B,HW,C)  (unchanged).
//  K2: grid (N, 2): block = (roi, CHANNEL-half). 128 channels per block;
//      lane = 4 channels (float4) -> 32 float4-columns; each wave handles
//      TWO bins per instruction (half-wave 0 = bin i, half-wave 1 = bin i+1).
//      LDS: stage 49x132 floats (25.9 KB) + geometry (3.1 KB) = 29 KB ->
//      5 blocks/CU (20 waves/CU; R5/R6 were LDS-capped at 2). Output per
//      block is one contiguous 25088 B span -> no cross-block line sharing
//      (R7's bin-split caused 5x write amplification via partial-line RMW).
// Numerics identical to R2-R6 (same per-component op order) — absmax 0.0156.

namespace {

constexpr int B_ = 4, C_ = 256, H_ = 50, W_ = 50;
constexpr int HW = H_ * W_;                     // 2500
constexpr int HO = 7, WO = 7, NBIN = HO * WO;   // 49
constexpr int OUT_PER_ROI = C_ * NBIN;          // 12544
constexpr int CPB = 128;                        // channels per block
constexpr int COLS = CPB / 4;                   // 32 float4 columns
constexpr int LDs = 132;                        // stage leading dim (mult of 4)
constexpr float RATIO = 1.0f / 32.0f;

// ---------------- K1: tiled transpose (B,C,HW) -> (B,HW,C) ----------------
__global__ __launch_bounds__(256) void transpose_tiled(
    const float* __restrict__ f, float* __restrict__ ft)
{
    __shared__ float tile[64][65];
    const int bt   = blockIdx.x;
    const int hw_t = bt % 40;
    const int c_t  = (bt / 40) % 4;
    const int b    = bt / 160;
    const int hw0 = hw_t * 64, c0 = c_t * 64;
    const int lx = threadIdx.x & 63;
    const int ly = threadIdx.x >> 6;

#pragma unroll
    for (int k = 0; k < 16; ++k) {
        const int c  = c0 + k * 4 + ly;
        const int hw = hw0 + lx;
        if (hw < HW)
            tile[k * 4 + ly][lx] = f[((size_t)b * C_ + c) * HW + hw];
    }
    __syncthreads();
#pragma unroll
    for (int k = 0; k < 16; ++k) {
        const int hw = hw0 + k * 4 + ly;
        if (hw < HW)
            ft[((size_t)b * HW + hw) * C_ + c0 + lx] = tile[lx][k * 4 + ly];
    }
}

// ---------------- K2: main ----------------
__global__ __launch_bounds__(256, 5) void roialign_main(
    const float* __restrict__ ft,       // (B,HW,C)
    const float* __restrict__ rois,
    float* __restrict__ out)
{
    __shared__ float stage[NBIN * LDs];                  // 25872 B
    __shared__ __align__(16) float    wts[NBIN][8];      // wxh0,wxh1,wxl0,wxl1,wyb0,wyb1,wyt0,wyt1 (x valid)
    __shared__ __align__(16) unsigned offs[NBIN][8];     // per sample s: [2s]=tl|tr<<16, [2s+1]=bl|br<<16

    const int n    = blockIdx.x;
    const int half = blockIdx.y;
    const int tid  = threadIdx.x;
    const int wave = tid >> 6;
    const int lane = tid & 63;
    const int col  = lane & 31;                          // float4 column 0..31
    const int sub  = lane >> 5;                          // which bin of the pair
    const float fW = (float)W_, fH = (float)H_;

    // ---- Phase 1: per-bin geometry (threads 0..48) ----
    if (tid < NBIN) {
        const int ii = tid / WO, jj = tid % WO;
        const float* r = rois + n * 5;
        const float bx1 = fminf(fmaxf(r[1] * RATIO, 0.0f), fW);
        const float by1 = fminf(fmaxf(r[2] * RATIO, 0.0f), fH);
        const float bx2 = fminf(fmaxf(r[3] * RATIO, 0.0f), fW);
        const float by2 = fminf(fmaxf(r[4] * RATIO, 0.0f), fH);
        const bool roi_valid = (bx2 - bx1 > 0.0f) && (by2 - by1 > 0.0f);
        const float bin_w = (bx2 - bx1) * (1.0f / (float)WO);
        const float bin_h = (by2 - by1) * (1.0f / (float)HO);

        const float x1u = bx1 + (float)jj * bin_w;
        const float x1b = fminf(fmaxf(x1u, 0.0f), fW);
        const float x2b = fminf(fmaxf(x1u + bin_w, 0.0f), fW);
        const float y1u = by1 + (float)ii * bin_h;
        const float y1b = fminf(fmaxf(y1u, 0.0f), fH);
        const float y2b = fminf(fmaxf(y1u + bin_h, 0.0f), fH);
        const float vf = (roi_valid && (y2b > y1b) && (x2b > x1b)) ? 1.0f : 0.0f;

        int xl[2], xh[2], yl[2], yh[2];
#pragma unroll
        for (int s = 0; s < 2; ++s) {
            const float px = x1b + ((float)s + 0.5f) * (bin_w * 0.5f);
            int l = (int)floorf(px);
            l = min(max(l, 0), W_ - 1);
            const int h = min(l + 1, W_ - 1);
            xl[s] = l; xh[s] = h;
            wts[tid][0 + s] = vf * (px - (float)l);      // wxh[s]
            wts[tid][2 + s] = vf * ((float)h - px);      // wxl[s]

            const float py = y1b + ((float)s + 0.5f) * (bin_h * 0.5f);
            int t = (int)floorf(py);
            t = min(max(t, 0), H_ - 1);
            const int u = min(t + 1, H_ - 1);
            yl[s] = t; yh[s] = u;
            wts[tid][4 + s] = py - (float)t;             // wyb[s]
            wts[tid][6 + s] = (float)u - py;             // wyt[s]
        }
#pragma unroll
        for (int sy = 0; sy < 2; ++sy) {
#pragma unroll
            for (int sx = 0; sx < 2; ++sx) {
                const int s = sy * 2 + sx;
                const unsigned tl = (unsigned)(yl[sy] * W_ + xl[sx]);
                const unsigned tr = (unsigned)(yl[sy] * W_ + xh[sx]);
                const unsigned bl = (unsigned)(yh[sy] * W_ + xl[sx]);
                const unsigned br = (unsigned)(yh[sy] * W_ + xh[sx]);
                offs[tid][s * 2 + 0] = tl | (tr << 16);
                offs[tid][s * 2 + 1] = bl | (br << 16);
            }
        }
    }
    __syncthreads();

    // ---- Phase 2: half-waves = bins, cols = 4-channel groups ----
    int b = (int)rois[n * 5];
    b = min(max(b, 0), B_ - 1);
    // float4 view of this (batch, channel-half): row = 64 float4s
    const float4* pb = (const float4*)(ft + (size_t)b * HW * C_) + half * COLS + col;

    for (int i0 = wave * 2; i0 < NBIN; i0 += 8) {
        const int bin = i0 + sub;                        // per half-wave
        const int bc  = min(bin, NBIN - 1);              // clamp lane 32.. tail
        const float4 wa = *(const float4*)wts[bc];       // wxh0,wxh1,wxl0,wxl1
        const float4 wb = *(const float4*)(wts[bc] + 4); // wyb0,wyb1,wyt0,wyt1
        const uint4  oa = *(const uint4*)&offs[bc][0];   // samples 0,1
        const uint4  ob = *(const uint4*)&offs[bc][4];   // samples 2,3

        auto samp = [&](unsigned ptop, unsigned pbot,
                        float wxh, float wxl, float wyb, float wyt) -> float4 {
            const int tl = (int)(ptop & 0xffffu) << 6;   // hw * 64 float4s
            const int tr = (int)(ptop >> 16) << 6;
            const int bl = (int)(pbot & 0xffffu) << 6;
            const int br = (int)(pbot >> 16) << 6;
            const float4 v_tl = pb[tl], v_tr = pb[tr];
            const float4 v_bl = pb[bl], v_br = pb[br];
            float4 o;
            o.x = wyb * (wxh * v_br.x + wxl * v_bl.x) + wyt * (wxh * v_tr.x + wxl * v_tl.x);
            o.y = wyb * (wxh * v_br.y + wxl * v_bl.y) + wyt * (wxh * v_tr.y + wxl * v_tl.y);
            o.z = wyb * (wxh * v_br.z + wxl * v_bl.z) + wyt * (wxh * v_tr.z + wxl * v_tl.z);
            o.w = wyb * (wxh * v_br.w + wxl * v_bl.w) + wyt * (wxh * v_tr.w + wxl * v_tl.w);
            return o;
        };

        const float4 s0 = samp(oa.x, oa.y, wa.x, wa.z, wb.x, wb.z); // sy0,sx0
        const float4 s1 = samp(oa.z, oa.w, wa.y, wa.w, wb.x, wb.z); // sy0,sx1
        const float4 s2 = samp(ob.x, ob.y, wa.x, wa.z, wb.y, wb.w); // sy1,sx0
        const float4 s3 = samp(ob.z, ob.w, wa.y, wa.w, wb.y, wb.w); // sy1,sx1
        float4 m;
        m.x = fmaxf(fmaxf(s0.x, s1.x), fmaxf(s2.x, s3.x));
        m.y = fmaxf(fmaxf(s0.y, s1.y), fmaxf(s2.y, s3.y));
        m.z = fmaxf(fmaxf(s0.z, s1.z), fmaxf(s2.z, s3.z));
        m.w = fmaxf(fmaxf(s0.w, s1.w), fmaxf(s2.w, s3.w));

        if (bin < NBIN)
            *(float4*)&stage[bin * LDs + 4 * col] = m;   // conflict-free b128
    }
    __syncthreads();

    // ---- Phase 3: one contiguous 25088B span per block ----
    float* outn = out + (size_t)n * OUT_PER_ROI + half * (CPB * NBIN);
    for (int k = tid; k < CPB * NBIN; k += 256) {
        const int ch = k / NBIN;                         // 0..127 (magic mul)
        const int bi = k - ch * NBIN;
        outn[k] = stage[bi * LDs + ch];
    }
}

} // namespace

extern "C" void kernel_launch(void* const* d_in, const int* in_sizes, int n_in,
                              void* d_out, int out_size, void* d_ws, size_t ws_size,
                              hipStream_t stream)
{
    const float* feats = (const float*)d_in[0];
    const float* rois  = (const float*)d_in[1];
    float* out = (float*)d_out;
    const int N = in_sizes[1] / 5;                    // 1024
    float* ft = (float*)d_ws;                         // 10.24 MB

    hipLaunchKernelGGL(transpose_tiled, dim3(B_ * 4 * 40), dim3(256), 0, stream,
                       feats, ft);
    hipLaunchKernelGGL(roialign_main, dim3(N, 2), dim3(256), 0, stream,
                       ft, rois, out);
}